// Round 9
// baseline (286.415 us; speedup 1.0000x reference)
//
#include <hip/hip_runtime.h>
#include <math.h>

typedef __attribute__((ext_vector_type(8))) short short8;
typedef __attribute__((ext_vector_type(4))) float f32x4;

namespace {
constexpr int BATCH = 4096;
constexpr int SEQT  = 256;
constexpr int INSZ  = 24;
constexpr int H     = 40;
constexpr int NOUT  = 24;
constexpr int R     = 16;    // batch rows per block, grid = 256 (1 block/CU)
constexpr int NT    = 128;   // 2 waves: 0 = recurrence (barrier-free), 1 = FC + x-stage
constexpr int NRS   = 16;    // ring slots (x|h A-tiles), 2KB each -> 32 KB LDS

__device__ __forceinline__ unsigned short f2bf(float f) {
  unsigned int u = __float_as_uint(f);
  return (unsigned short)((u + 0x7FFFu + ((u >> 16) & 1u)) >> 16);  // RNE
}
__device__ __forceinline__ unsigned int pack2(float a, float b) {
  return (unsigned)f2bf(a) | ((unsigned)f2bf(b) << 16);
}
__device__ __forceinline__ float4 ld4(const float* p) {
  return *reinterpret_cast<const float4*>(p);
}
// Native-rate transcendentals (v_exp_f32/v_rcp_f32) — avoids IEEE div sequence.
__device__ __forceinline__ float sigm(float v) {
  return __builtin_amdgcn_rcpf(1.0f + __builtin_amdgcn_exp2f(v * -1.442695041f));
}
__device__ __forceinline__ float tanh_fast(float v) {
  return fmaf(2.0f,
              __builtin_amdgcn_rcpf(1.0f + __builtin_amdgcn_exp2f(v * -2.885390082f)),
              -1.0f);
}
}  // namespace

// Superstep barrier (every 4 steps): drain LDS, sync both waves.
#define BAR()                                              \
  asm volatile("s_waitcnt lgkmcnt(0)" ::: "memory");       \
  __builtin_amdgcn_s_barrier();                            \
  __builtin_amdgcn_sched_barrier(0);

// Ring slot s holds A(t)=[x(t) k0..23 | h(t-1) k24..63] bf16, s = t mod 16,
// swizzle idx^=(row&7)<<3. Rec wave owns the whole h-recurrence (3 u-tiles x
// 4 zones = 24 MFMAs/step, B-frags in regs) -> h writeback/readback is an
// IN-WAVE LDS RAW, no per-step barrier. FC wave lags 4 steps; x staged 8 ahead.
// Slot sets per superstep (mod 16): rec-read {0..3}, rec-write {1..4},
// FC-read {13,14,15,0}, stage-write {8..11} — disjoint where it matters.
__global__ __launch_bounds__(NT, 1) void gru_ring(
    const float* __restrict__ x, const float* __restrict__ Wih,
    const float* __restrict__ Whh, const float* __restrict__ bih,
    const float* __restrict__ bhh, const float* __restrict__ Wfc,
    const float* __restrict__ bfc, float* __restrict__ out,
    float* __restrict__ hid) {
  __shared__ __align__(16) unsigned short ring[NRS * 1024];

  const int tid = threadIdx.x;
  const int l   = tid & 63;
  const int w   = tid >> 6;
  const int lm  = l & 15;
  const int lq  = l >> 4;
  const int gb0 = blockIdx.x * R;

  // zero slot 0 (h(-1) = 0); 128 threads x 16B = 2048B
  reinterpret_cast<uint4*>(ring)[tid] = make_uint4(0, 0, 0, 0);

  const int aBase0 = ((lm * 64 + lq * 8)      ^ ((lm & 7) << 3));
  const int aBase1 = ((lm * 64 + lq * 8 + 32) ^ ((lm & 7) << 3));

  // ---------------- rec wave (w==0): all 3 u-tiles ----------------
  short8 B[3][4][2];
  float bias[3][4];
  float hold[3][4];
  int awr[3][4];
  bool gv[3] = {false, false, false};
  if (w == 0) {
#pragma unroll
    for (int g = 0; g < 3; ++g) {
      const int u = g * 16 + lm;
      const bool val = (u < H);
      gv[g] = val;
#pragma unroll
      for (int z = 0; z < 4; ++z) {
#pragma unroll
        for (int kt = 0; kt < 2; ++kt) {
          short8 b;
#pragma unroll
          for (int j = 0; j < 8; ++j) {
            const int k = kt * 32 + lq * 8 + j;
            float v = 0.0f;
            if (val) {
              if (z == 0)      v = (k < 24) ? Wih[u * 24 + k]        : Whh[u * 40 + (k - 24)];
              else if (z == 1) v = (k < 24) ? Wih[(40 + u) * 24 + k] : Whh[(40 + u) * 40 + (k - 24)];
              else if (z == 2) v = (k < 24) ? Wih[(80 + u) * 24 + k] : 0.0f;
              else             v = (k < 24) ? 0.0f                   : Whh[(80 + u) * 40 + (k - 24)];
            }
            b[j] = (short)f2bf(v);
          }
          B[g][z][kt] = b;
        }
      }
      bias[g][0] = val ? bih[u] + bhh[u] : 0.0f;
      bias[g][1] = val ? bih[40 + u] + bhh[40 + u] : 0.0f;
      bias[g][2] = val ? bih[80 + u] : 0.0f;   // n input bias
      bias[g][3] = val ? bhh[80 + u] : 0.0f;   // n hidden bias (scaled by r)
#pragma unroll
      for (int i = 0; i < 4; ++i) {
        const int row = lq * 4 + i;
        awr[g][i] = ((row * 64 + 24 + u) ^ ((row & 7) << 3));
        hold[g][i] = 0.0f;
      }
    }
  }

  // ---------------- FC + stage wave (w==1) ----------------
  short8 F[2][2];
  float biasF[2] = {0, 0};
  float* orow[4] = {nullptr, nullptr, nullptr, nullptr};
  if (w == 1) {
#pragma unroll
    for (int f = 0; f < 2; ++f) {
      const int o = f * 16 + lm;
#pragma unroll
      for (int kt = 0; kt < 2; ++kt) {
        short8 b;
#pragma unroll
        for (int j = 0; j < 8; ++j) {
          const int k = kt * 32 + lq * 8 + j;
          const float v = (o < NOUT && k >= 24) ? Wfc[o * H + (k - 24)] : 0.0f;
          b[j] = (short)f2bf(v);
        }
        F[f][kt] = b;
      }
      biasF[f] = (o < NOUT) ? bfc[o] : 0.0f;
    }
#pragma unroll
    for (int i = 0; i < 4; ++i)
      orow[i] = out + ((size_t)(gb0 + lq * 4 + i) * SEQT) * NOUT;
  }

  BAR();  // slot-0 zero visible before x staging overwrites its x-part

  // prologue: stage x(0..7) into slots 0..7 (768 float4 chunks, 12/lane)
  if (w == 1) {
#pragma unroll
    for (int st = 0; st < 12; ++st) {
      const int item = st * 64 + l;          // 0..767
      const int stp  = item / 96;            // step 0..7
      const int win  = item - stp * 96;
      const int row  = win / 6;
      const int c4   = (win - row * 6) * 4;
      const float4 v = ld4(x + ((size_t)(gb0 + row) * SEQT + stp) * INSZ + c4);
      const int xi = (stp << 10) + ((row * 64 + c4) ^ ((row & 7) << 3));
      *reinterpret_cast<uint2*>(&ring[xi]) = make_uint2(pack2(v.x, v.y), pack2(v.z, v.w));
    }
  }
  BAR();  // x(0..7) staged before rec starts

#define REC_STEP(T)                                                             \
  {                                                                             \
    const int so = ((T) & (NRS - 1)) << 10;                                     \
    const int sn = (((T) + 1) & (NRS - 1)) << 10;                               \
    const short8 A0 = *reinterpret_cast<const short8*>(&ring[so + aBase0]);     \
    const short8 A1 = *reinterpret_cast<const short8*>(&ring[so + aBase1]);     \
    _Pragma("unroll")                                                           \
    for (int g = 0; g < 3; ++g) {                                               \
      f32x4 ar = {bias[g][0], bias[g][0], bias[g][0], bias[g][0]};              \
      f32x4 az = {bias[g][1], bias[g][1], bias[g][1], bias[g][1]};              \
      f32x4 ax = {bias[g][2], bias[g][2], bias[g][2], bias[g][2]};              \
      f32x4 ah = {bias[g][3], bias[g][3], bias[g][3], bias[g][3]};              \
      ar = __builtin_amdgcn_mfma_f32_16x16x32_bf16(A0, B[g][0][0], ar, 0, 0, 0);\
      az = __builtin_amdgcn_mfma_f32_16x16x32_bf16(A0, B[g][1][0], az, 0, 0, 0);\
      ax = __builtin_amdgcn_mfma_f32_16x16x32_bf16(A0, B[g][2][0], ax, 0, 0, 0);\
      ah = __builtin_amdgcn_mfma_f32_16x16x32_bf16(A0, B[g][3][0], ah, 0, 0, 0);\
      ar = __builtin_amdgcn_mfma_f32_16x16x32_bf16(A1, B[g][0][1], ar, 0, 0, 0);\
      az = __builtin_amdgcn_mfma_f32_16x16x32_bf16(A1, B[g][1][1], az, 0, 0, 0);\
      ax = __builtin_amdgcn_mfma_f32_16x16x32_bf16(A1, B[g][2][1], ax, 0, 0, 0);\
      ah = __builtin_amdgcn_mfma_f32_16x16x32_bf16(A1, B[g][3][1], ah, 0, 0, 0);\
      _Pragma("unroll")                                                         \
      for (int i = 0; i < 4; ++i) {                                             \
        const float rr = sigm(ar[i]);                                           \
        const float zz = sigm(az[i]);                                           \
        const float nn = tanh_fast(fmaf(rr, ah[i], ax[i]));                     \
        const float h  = fmaf(zz, hold[g][i] - nn, nn);                         \
        hold[g][i] = h;                                                         \
        if (gv[g]) ring[sn + awr[g][i]] = f2bf(h);                              \
      }                                                                         \
    }                                                                           \
  }

#define FC_STEP(T)                                                              \
  {                                                                             \
    const int so = (((T) + 1) & (NRS - 1)) << 10;                               \
    const short8 hA0 = *reinterpret_cast<const short8*>(&ring[so + aBase0]);    \
    const short8 hA1 = *reinterpret_cast<const short8*>(&ring[so + aBase1]);    \
    f32x4 f0 = {biasF[0], biasF[0], biasF[0], biasF[0]};                        \
    f32x4 f1 = {biasF[1], biasF[1], biasF[1], biasF[1]};                        \
    f0 = __builtin_amdgcn_mfma_f32_16x16x32_bf16(hA0, F[0][0], f0, 0, 0, 0);    \
    f1 = __builtin_amdgcn_mfma_f32_16x16x32_bf16(hA0, F[1][0], f1, 0, 0, 0);    \
    f0 = __builtin_amdgcn_mfma_f32_16x16x32_bf16(hA1, F[0][1], f0, 0, 0, 0);    \
    f1 = __builtin_amdgcn_mfma_f32_16x16x32_bf16(hA1, F[1][1], f1, 0, 0, 0);    \
    _Pragma("unroll")                                                           \
    for (int i = 0; i < 4; ++i) {                                               \
      orow[i][(size_t)(T) * NOUT + lm] = sigm(f0[i]);                           \
      if (lm < 8) orow[i][(size_t)(T) * NOUT + 16 + lm] = sigm(f1[i]);          \
    }                                                                           \
  }

  for (int S = 0; S < 65; ++S) {
    if (w == 0) {
      if (S < 64) {
        const int t0 = S * 4;
        REC_STEP(t0 + 0)
        REC_STEP(t0 + 1)
        REC_STEP(t0 + 2)
        REC_STEP(t0 + 3)
      }
    } else {
      if (S >= 1) {
        const int tp = (S - 1) * 4;
        FC_STEP(tp + 0)
        FC_STEP(tp + 1)
        FC_STEP(tp + 2)
        FC_STEP(tp + 3)
      }
      if (S <= 61) {  // stage x(4S+8 .. 4S+11) into slots (.. mod 16)
        const int base = S * 4 + 8;
#pragma unroll
        for (int st = 0; st < 6; ++st) {
          const int item = st * 64 + l;      // 0..383
          const int stp  = item / 96;        // 0..3
          const int win  = item - stp * 96;
          const int row  = win / 6;
          const int c4   = (win - row * 6) * 4;
          const int t2   = base + stp;
          const float4 v = ld4(x + ((size_t)(gb0 + row) * SEQT + t2) * INSZ + c4);
          const int xi = ((t2 & (NRS - 1)) << 10) + ((row * 64 + c4) ^ ((row & 7) << 3));
          *reinterpret_cast<uint2*>(&ring[xi]) =
              make_uint2(pack2(v.x, v.y), pack2(v.z, v.w));
        }
      }
    }
    BAR();
  }

  // final hidden state from rec wave's fp32 registers
  if (w == 0) {
#pragma unroll
    for (int g = 0; g < 3; ++g) {
      if (gv[g]) {
#pragma unroll
        for (int i = 0; i < 4; ++i)
          hid[(size_t)(gb0 + lq * 4 + i) * H + (g * 16 + lm)] = hold[g][i];
      }
    }
  }
}

extern "C" void kernel_launch(void* const* d_in, const int* in_sizes, int n_in,
                              void* d_out, int out_size, void* d_ws, size_t ws_size,
                              hipStream_t stream) {
  const float* x   = (const float*)d_in[0];
  const float* Wih = (const float*)d_in[1];
  const float* Whh = (const float*)d_in[2];
  const float* bih = (const float*)d_in[3];
  const float* bhh = (const float*)d_in[4];
  const float* Wfc = (const float*)d_in[5];
  const float* bfc = (const float*)d_in[6];
  float* out = (float*)d_out;
  float* hid = out + (size_t)BATCH * SEQT * NOUT;

  dim3 grid(BATCH / R);
  dim3 block(NT);
  hipLaunchKernelGGL(gru_ring, grid, block, 0, stream,
                     x, Wih, Whh, bih, bhh, Wfc, bfc, out, hid);
}

// Round 10
// 134.951 us; speedup vs baseline: 2.1224x; 2.1224x over previous
//
#include <hip/hip_runtime.h>
#include <math.h>

typedef __attribute__((ext_vector_type(8))) short short8;
typedef __attribute__((ext_vector_type(4))) float f32x4;

namespace {
constexpr int BATCH = 4096;
constexpr int SEQT  = 256;
constexpr int INSZ  = 24;
constexpr int H     = 40;
constexpr int NOUT  = 24;
constexpr int R     = 16;    // batch rows per block, grid = 256 (1 block/CU)
constexpr int NT    = 256;   // 4 waves: 0-2 gate tiles, 3 = x-stage + FC(lagged)

__device__ __forceinline__ unsigned short f2bf(float f) {
  unsigned int u = __float_as_uint(f);
  return (unsigned short)((u + 0x7FFFu + ((u >> 16) & 1u)) >> 16);  // RNE
}
__device__ __forceinline__ unsigned short cvt_bf16(float f) {
  float r;
  asm("v_cvt_pk_bf16_f32 %0, %1, %2" : "=v"(r) : "v"(f), "v"(f));
  return (unsigned short)__float_as_uint(r);   // low 16 bits = bf16(f), RNE
}
__device__ __forceinline__ float4 ld4(const float* p) {
  return *reinterpret_cast<const float4*>(p);
}
// Native-rate transcendentals (v_exp_f32/v_rcp_f32) — avoids IEEE div sequence.
__device__ __forceinline__ float sigm(float v) {
  return __builtin_amdgcn_rcpf(1.0f + __builtin_amdgcn_exp2f(v * -1.442695041f));
}
__device__ __forceinline__ float tanh_fast(float v) {
  return fmaf(2.0f,
              __builtin_amdgcn_rcpf(1.0f + __builtin_amdgcn_exp2f(v * -2.885390082f)),
              -1.0f);
}
}  // namespace

// Raw barrier: drain only LDS ops; global loads/stores stay in flight.
#define BAR()                                              \
  asm volatile("s_waitcnt lgkmcnt(0)" ::: "memory");       \
  __builtin_amdgcn_s_barrier();                            \
  __builtin_amdgcn_sched_barrier(0);

// Interval t: every wave READS only buffer bo=(t&1) and WRITES only nbo.
//   gates: A(t)=[x(t)|h(t-1)] from bo -> 7 MFMA -> gate math -> h(t)->nbo
//   w3:    stage x(t+1)->nbo (prefetched 2 intervals ago), FC(t-1) from bo
// FC is lagged one interval so it starts with data already visible; its x-row
// weights are zero so reading the x-part is harmless. nx kt=1 MFMA dropped
// (B tile provably zero: k=32..63 are all h-cols, nx has none).
__global__ __launch_bounds__(NT) void gru_mfma4(
    const float* __restrict__ x, const float* __restrict__ Wih,
    const float* __restrict__ Whh, const float* __restrict__ bih,
    const float* __restrict__ bhh, const float* __restrict__ Wfc,
    const float* __restrict__ bfc, float* __restrict__ out,
    float* __restrict__ hid) {
  __shared__ __align__(16) unsigned short Abuf[2 * 1024];

  const int tid = threadIdx.x;
  const int l   = tid & 63;
  const int w   = tid >> 6;
  const int lm  = l & 15;
  const int lq  = l >> 4;
  const int gb0 = blockIdx.x * R;

  reinterpret_cast<uint4*>(Abuf)[tid] = make_uint4(0, 0, 0, 0);  // zero both buffers

  const int aBase0 = ((lm * 64 + lq * 8)      ^ ((lm & 7) << 3));
  const int aBase1 = ((lm * 64 + lq * 8 + 32) ^ ((lm & 7) << 3));

  // ---------------- gate role (waves 0..2) ----------------
  short8 B[4][2];
  float bias[4] = {0, 0, 0, 0};
  float hold[4] = {0, 0, 0, 0};
  int aw[4] = {0, 0, 0, 0};
  int u = 0;
  bool gvalid = false;
  if (w < 3) {
    u = w * 16 + lm;
    gvalid = (u < H);
#pragma unroll
    for (int z = 0; z < 4; ++z) {
#pragma unroll
      for (int kt = 0; kt < 2; ++kt) {
        short8 b;
#pragma unroll
        for (int j = 0; j < 8; ++j) {
          const int k = kt * 32 + lq * 8 + j;
          float v = 0.0f;
          if (gvalid) {
            if (z == 0)      v = (k < 24) ? Wih[u * 24 + k]          : Whh[u * 40 + (k - 24)];
            else if (z == 1) v = (k < 24) ? Wih[(40 + u) * 24 + k]   : Whh[(40 + u) * 40 + (k - 24)];
            else if (z == 2) v = (k < 24) ? Wih[(80 + u) * 24 + k]   : 0.0f;
            else             v = (k < 24) ? 0.0f                     : Whh[(80 + u) * 40 + (k - 24)];
          }
          b[j] = (short)f2bf(v);
        }
        B[z][kt] = b;
      }
    }
    if (gvalid) {
      bias[0] = bih[u] + bhh[u];
      bias[1] = bih[40 + u] + bhh[40 + u];
      bias[2] = bih[80 + u];           // n input bias
      bias[3] = bhh[80 + u];           // n hidden bias (scaled by r)
    }
#pragma unroll
    for (int i = 0; i < 4; ++i)
      aw[i] = (((lq * 4 + i) * 64 + 24 + u) ^ (((lq * 4 + i) & 7) << 3));
  }

  // ---------------- x-stage + FC role (wave 3) ----------------
  short8 F[2][2];
  float biasF[2] = {0, 0};
  float* orow[4] = {nullptr, nullptr, nullptr, nullptr};
  const float* xp0 = nullptr;
  const float* xp1 = nullptr;
  int xw0 = 0, xw1 = 0;
  bool x1v = false;
  float4 xA0 = make_float4(0,0,0,0), xA1 = make_float4(0,0,0,0);
  float4 xB0 = make_float4(0,0,0,0), xB1 = make_float4(0,0,0,0);
  if (w == 3) {
#pragma unroll
    for (int f = 0; f < 2; ++f) {
      const int o = f * 16 + lm;
#pragma unroll
      for (int kt = 0; kt < 2; ++kt) {
        short8 b;
#pragma unroll
        for (int j = 0; j < 8; ++j) {
          const int k = kt * 32 + lq * 8 + j;
          const float v = (o < NOUT && k >= 24) ? Wfc[o * H + (k - 24)] : 0.0f;
          b[j] = (short)f2bf(v);
        }
        F[f][kt] = b;
      }
      biasF[f] = (o < NOUT) ? bfc[o] : 0.0f;
    }
#pragma unroll
    for (int i = 0; i < 4; ++i)
      orow[i] = out + ((size_t)(gb0 + lq * 4 + i) * SEQT) * NOUT;

    // x staging: 96 float4 chunks (16 rows x 6), items l and 64+l (l<32)
    const int i0 = l, i1 = 64 + l;
    const int xr0 = i0 / 6, xc0 = (i0 - xr0 * 6) * 4;
    const int xr1 = i1 / 6, xc1 = (i1 - xr1 * 6) * 4;
    x1v = (l < 32);
    xp0 = x + ((size_t)(gb0 + xr0) * SEQT) * INSZ + xc0;
    if (x1v) xp1 = x + ((size_t)(gb0 + xr1) * SEQT) * INSZ + xc1;
    xw0 = ((xr0 * 64 + xc0) ^ ((xr0 & 7) << 3));
    xw1 = ((xr1 * 64 + xc1) ^ ((xr1 & 7) << 3));
  }

  __syncthreads();  // zero-init visible

  if (w == 3) {  // stage x(0) into buf0; prefetch x(1)->xA, x(2)->xB
    const float4 v0 = ld4(xp0);
    *reinterpret_cast<uint2*>(&Abuf[xw0]) = make_uint2(
        (unsigned)f2bf(v0.x) | ((unsigned)f2bf(v0.y) << 16),
        (unsigned)f2bf(v0.z) | ((unsigned)f2bf(v0.w) << 16));
    if (x1v) {
      const float4 v1 = ld4(xp1);
      *reinterpret_cast<uint2*>(&Abuf[xw1]) = make_uint2(
          (unsigned)f2bf(v1.x) | ((unsigned)f2bf(v1.y) << 16),
          (unsigned)f2bf(v1.z) | ((unsigned)f2bf(v1.w) << 16));
    }
    xA0 = ld4(xp0 + 1 * INSZ);
    xB0 = ld4(xp0 + 2 * INSZ);
    if (x1v) { xA1 = ld4(xp1 + 1 * INSZ); xB1 = ld4(xp1 + 2 * INSZ); }
  }
  __syncthreads();  // x(0) staged

// 7-MFMA gate step (nx kt=1 tile is identically zero -> skipped)
#define GATE_STEP(BO, NBO)                                                      \
  if (w < 3) {                                                                  \
    const short8 A0 = *reinterpret_cast<const short8*>(&Abuf[(BO) + aBase0]);   \
    const short8 A1 = *reinterpret_cast<const short8*>(&Abuf[(BO) + aBase1]);   \
    f32x4 ar = {bias[0], bias[0], bias[0], bias[0]};                            \
    f32x4 az = {bias[1], bias[1], bias[1], bias[1]};                            \
    f32x4 ax = {bias[2], bias[2], bias[2], bias[2]};                            \
    f32x4 ah = {bias[3], bias[3], bias[3], bias[3]};                            \
    ar = __builtin_amdgcn_mfma_f32_16x16x32_bf16(A0, B[0][0], ar, 0, 0, 0);     \
    az = __builtin_amdgcn_mfma_f32_16x16x32_bf16(A0, B[1][0], az, 0, 0, 0);     \
    ax = __builtin_amdgcn_mfma_f32_16x16x32_bf16(A0, B[2][0], ax, 0, 0, 0);     \
    ah = __builtin_amdgcn_mfma_f32_16x16x32_bf16(A0, B[3][0], ah, 0, 0, 0);     \
    ar = __builtin_amdgcn_mfma_f32_16x16x32_bf16(A1, B[0][1], ar, 0, 0, 0);     \
    az = __builtin_amdgcn_mfma_f32_16x16x32_bf16(A1, B[1][1], az, 0, 0, 0);     \
    ah = __builtin_amdgcn_mfma_f32_16x16x32_bf16(A1, B[3][1], ah, 0, 0, 0);     \
    _Pragma("unroll")                                                           \
    for (int i = 0; i < 4; ++i) {                                               \
      const float rr = sigm(ar[i]);                                             \
      const float zz = sigm(az[i]);                                             \
      const float nn = tanh_fast(fmaf(rr, ah[i], ax[i]));                       \
      const float h  = fmaf(zz, hold[i] - nn, nn);                              \
      hold[i] = h;                                                              \
      if (gvalid) Abuf[(NBO) + aw[i]] = cvt_bf16(h);                            \
    }                                                                           \
  }

// stage x(T) into buffer TBO from reg XS; reload XS <- x(T+2)
#define XSTAGE(T, TBO, XS0, XS1)                                                \
  {                                                                             \
    if ((T) < SEQT) {                                                           \
      *reinterpret_cast<uint2*>(&Abuf[(TBO) + xw0]) = make_uint2(               \
          (unsigned)f2bf(XS0.x) | ((unsigned)f2bf(XS0.y) << 16),                \
          (unsigned)f2bf(XS0.z) | ((unsigned)f2bf(XS0.w) << 16));               \
      if (x1v)                                                                  \
        *reinterpret_cast<uint2*>(&Abuf[(TBO) + xw1]) = make_uint2(             \
            (unsigned)f2bf(XS1.x) | ((unsigned)f2bf(XS1.y) << 16),              \
            (unsigned)f2bf(XS1.z) | ((unsigned)f2bf(XS1.w) << 16));             \
    }                                                                           \
    if ((T) + 2 < SEQT) {                                                       \
      XS0 = ld4(xp0 + (size_t)((T) + 2) * INSZ);                                \
      if (x1v) XS1 = ld4(xp1 + (size_t)((T) + 2) * INSZ);                       \
    }                                                                           \
  }

// FC for step T, reading buffer BO (= buffer holding h(T))
#define FC_STEP(T, BO)                                                          \
  {                                                                             \
    const short8 hA0 = *reinterpret_cast<const short8*>(&Abuf[(BO) + aBase0]);  \
    const short8 hA1 = *reinterpret_cast<const short8*>(&Abuf[(BO) + aBase1]);  \
    f32x4 f0 = {biasF[0], biasF[0], biasF[0], biasF[0]};                        \
    f32x4 f1 = {biasF[1], biasF[1], biasF[1], biasF[1]};                        \
    f0 = __builtin_amdgcn_mfma_f32_16x16x32_bf16(hA0, F[0][0], f0, 0, 0, 0);    \
    f1 = __builtin_amdgcn_mfma_f32_16x16x32_bf16(hA0, F[1][0], f1, 0, 0, 0);    \
    f0 = __builtin_amdgcn_mfma_f32_16x16x32_bf16(hA1, F[0][1], f0, 0, 0, 0);    \
    f1 = __builtin_amdgcn_mfma_f32_16x16x32_bf16(hA1, F[1][1], f1, 0, 0, 0);    \
    _Pragma("unroll")                                                           \
    for (int i = 0; i < 4; ++i) {                                               \
      orow[i][(size_t)(T) * NOUT + lm] = sigm(f0[i]);                           \
      if (lm < 8) orow[i][(size_t)(T) * NOUT + 16 + lm] = sigm(f1[i]);          \
    }                                                                           \
  }

  for (int tt = 0; tt < SEQT; tt += 2) {
    // ---- interval tt: bo=0, nbo=1024 ----
    GATE_STEP(0, 1024)
    if (w == 3) {
      XSTAGE(tt + 1, 1024, xA0, xA1)
      if (tt > 0) FC_STEP(tt - 1, 0)
    }
    BAR()
    // ---- interval tt+1: bo=1024, nbo=0 ----
    GATE_STEP(1024, 0)
    if (w == 3) {
      XSTAGE(tt + 2, 0, xB0, xB1)
      FC_STEP(tt, 1024)
    }
    BAR()
  }
  // epilogue: FC for the final step (h(255) lives in buf0)
  if (w == 3) FC_STEP(SEQT - 1, 0)

  // final hidden state from registers
  if (w < 3 && gvalid) {
#pragma unroll
    for (int i = 0; i < 4; ++i)
      hid[(size_t)(gb0 + lq * 4 + i) * H + u] = hold[i];
  }
}

extern "C" void kernel_launch(void* const* d_in, const int* in_sizes, int n_in,
                              void* d_out, int out_size, void* d_ws, size_t ws_size,
                              hipStream_t stream) {
  const float* x   = (const float*)d_in[0];
  const float* Wih = (const float*)d_in[1];
  const float* Whh = (const float*)d_in[2];
  const float* bih = (const float*)d_in[3];
  const float* bhh = (const float*)d_in[4];
  const float* Wfc = (const float*)d_in[5];
  const float* bfc = (const float*)d_in[6];
  float* out = (float*)d_out;
  float* hid = out + (size_t)BATCH * SEQT * NOUT;

  dim3 grid(BATCH / R);
  dim3 block(NT);
  hipLaunchKernelGGL(gru_mfma4, grid, block, 0, stream,
                     x, Wih, Whh, bih, bhh, Wfc, bfc, out, hid);
}